// Round 13
// baseline (2067.365 us; speedup 1.0000x reference)
//
#include <hip/hip_runtime.h>
#include <hip/hip_bf16.h>
#include <cstdint>
#include <cstddef>

#define HP 320   // padded hidden/N dim (300 -> 320)

typedef unsigned short ushortT;
typedef __attribute__((ext_vector_type(8))) __bf16 bf16x8;
typedef __attribute__((ext_vector_type(4))) float f32x4;

__device__ __forceinline__ float b2f(unsigned u) {
    union { unsigned i; float f; } v; v.i = u << 16; return v.f;
}
__device__ __forceinline__ ushortT f2b(float f) {
    union { float f; unsigned i; } v; v.f = f;
    unsigned x = v.i;
    return (ushortT)((x + 0x7fffu + ((x >> 16) & 1u)) >> 16);
}
__device__ __forceinline__ unsigned subpk(unsigned a, unsigned r) {
    union { unsigned i; float f; } al, ah, rl, rh;
    al.i = a << 16; ah.i = a & 0xffff0000u;
    rl.i = r << 16; rh.i = r & 0xffff0000u;
    float lo = al.f - rl.f, hi = ah.f - rh.f;
    return (unsigned)f2b(lo) | ((unsigned)f2b(hi) << 16);
}
__device__ __forceinline__ uint4 subpk4(uint4 a, uint4 r) {
    uint4 o;
    o.x = subpk(a.x, r.x); o.y = subpk(a.y, r.y);
    o.z = subpk(a.z, r.z); o.w = subpk(a.w, r.w);
    return o;
}

// global->LDS direct DMA, 16B per lane. LDS dest is WAVE-UNIFORM base; HW writes
// lane i's data at base + i*16. Global src is per-lane. No VGPR round-trip.
__device__ __forceinline__ void glds16(const ushortT* g, ushortT* l) {
    __builtin_amdgcn_global_load_lds(
        (const __attribute__((address_space(1))) void*)g,
        (__attribute__((address_space(3))) void*)l,
        16, 0, 0);
}

// ---------------------------------------------------------------- pack weights into MFMA B-fragment order
// packed[kt][nt(20)][kg(4)][col(16)][j(8)]  ==  W[kt*32+kg*8+j][nt*16+col]
__device__ __forceinline__ void pack_one(int idx, const float* __restrict__ W,
                                         int Ksrc, ushortT* __restrict__ dst) {
    int j = idx & 7, col = (idx >> 3) & 15, kg = (idx >> 7) & 3;
    int t = idx >> 9; int nt = t % 20, kt = t / 20;
    int k = kt * 32 + kg * 8 + j, n = nt * 16 + col;
    float v = (k < Ksrc && n < 300) ? W[k * 300 + n] : 0.f;
    dst[idx] = f2b(v);
}
// W_o remap: logical k<133 -> fa rows (src k), k in [160,460) -> amsg rows (src k-27), else 0
__device__ __forceinline__ void pack_wo(int idx, const float* __restrict__ W,
                                        ushortT* __restrict__ dst) {
    int j = idx & 7, col = (idx >> 3) & 15, kg = (idx >> 7) & 3;
    int t = idx >> 9; int nt = t % 20, kt = t / 20;
    int k = kt * 32 + kg * 8 + j, n = nt * 16 + col;
    int src = (k < 133) ? k : ((k >= 160 && k < 460) ? (k - 27) : -1);
    float v = (src >= 0 && n < 300) ? W[src * 300 + n] : 0.f;
    dst[idx] = f2b(v);
}

__global__ __launch_bounds__(256) void k_pack_weights(
    const float* __restrict__ Wi, const float* __restrict__ Wh,
    const float* __restrict__ Wo, const float* __restrict__ bo,
    ushortT* __restrict__ Wipk, ushortT* __restrict__ Whpk,
    ushortT* __restrict__ Wopk, float* __restrict__ bop) {
    int idx = blockIdx.x * 256 + threadIdx.x;
    if (idx < 51200)  pack_one(idx, Wi, 147, Wipk);   // K1 = 160 (5 ktiles)
    if (idx < 102400) pack_one(idx, Wh, 300, Whpk);   // K2 = 320 (10 ktiles)
    if (idx < 153600) pack_wo(idx, Wo, Wopk);         // K3 = 480 (15 ktiles)
    if (idx < HP) bop[idx] = (idx < 300) ? bo[idx] : 0.f;
}

// ---------------------------------------------------------------- pre-pack fp32 features -> bf16 [rows][160]
template <int FD>   // 147 (f_bonds) or 133 (f_atoms)
__global__ __launch_bounds__(256) void k_pack_feat(
    const float* __restrict__ src, ushortT* __restrict__ dst, int nrows) {
    int t = blockIdx.x * 256 + threadIdx.x;
    if (t >= nrows * 20) return;
    int row = t / 20, q = t - row * 20;
    int k0 = q * 8;
    union { ushortT u[8]; uint4 v; } o;
#pragma unroll
    for (int j = 0; j < 8; j++) {
        int k = k0 + j;
        o.u[j] = (k < FD) ? f2b(src[(size_t)row * FD + k]) : (ushortT)0;
    }
    *(uint4*)(dst + (size_t)row * 160 + k0) = o.v;
}

// ---------------------------------------------------------------- unified MFMA GEMM: counted-vmcnt 2-phase (T4)
// Full-K A panel staged in LDS prologue (no global loads inside K-loop), B tile
// (20KB/kt) double-buffered via global_load_lds. Per ktile: issue glds(kt+1) ->
// s_waitcnt vmcnt(5) (kt done, kt+1 IN FLIGHT across the barrier) -> raw s_barrier
// -> MFMA -> raw s_barrier (readers-done). kt+1's loads fly for a FULL iteration
// (2x R12's drain-to-0 syncthreads).
// MODE 0: A = fbb (K=160, panel [32][168]), B=Wipk.     out: msg = relu(A@Wi)
// MODE 1: A = [diff gathers K=320 | fbb K=160] panel [32][488], B=[Whpk|Wipk].
//         out: msg = relu(diff@Wh + fb@Wi)
// MODE 2: A = [faa K=160 | amsg K=320] panel [32][488], B=Wopk. out: ah=relu(A@Wo+b)
template <int MODE, bool AUXP>
__global__ __launch_bounds__(256, (MODE == 0) ? 3 : 2) void k_mfma(
    const float* __restrict__ fa, const float* __restrict__ fb,
    const ushortT* __restrict__ aux,
    const ushortT* __restrict__ amsg, const ushortT* __restrict__ msgin,
    const int* __restrict__ b2a, const int* __restrict__ b2revb,
    const ushortT* __restrict__ Bpk1, const ushortT* __restrict__ Bpk2,
    const float* __restrict__ bop,
    ushortT* __restrict__ outp) {
    constexpr int KT = (MODE == 0) ? 5 : 15;       // total ktiles
    constexpr int SPLIT = (MODE == 1) ? 10 : KT;   // B source switch point
    constexpr int CH = (MODE == 0) ? 20 : 60;      // 16B chunks per panel row
    constexpr int SP = (MODE == 0) ? 168 : 488;    // panel row stride (pad +8)
    __shared__ __align__(16) ushortT Bl[2][10240]; // 40 KB B dbuf
    __shared__ __align__(16) ushortT panel[32 * SP];

    const int tid = threadIdx.x, wave = tid >> 6, lane = tid & 63;
    const int row0 = blockIdx.x * 32;
    const int wm = wave >> 1, wn = wave & 1;
    const int kg8 = (lane >> 4) * 8;

    // ================= prologue 1: stage full-K A panel (regular loads; compiler waits)
#pragma unroll
    for (int it = 0; it < (32 * CH + 255) / 256; it++) {
        int flat = tid + 256 * it;
        if (flat < 32 * CH) {
            int row = flat / CH, ch = flat - row * CH;
            uint4 v;
            if (MODE == 1) {
                if (ch < 40) {                     // gathered diff, K in [0,320)
                    size_t oa = (size_t)b2a[row0 + row] * HP;
                    size_t orv = (size_t)b2revb[row0 + row] * HP;
                    uint4 ua = *(const uint4*)(amsg + oa + ch * 8);
                    uint4 ur = *(const uint4*)(msgin + orv + ch * 8);
                    v = subpk4(ua, ur);
                } else if (AUXP) {                 // fbb, K in [320,480)
                    v = *(const uint4*)(aux + (size_t)(row0 + row) * 160 + (ch - 40) * 8);
                } else {
                    union { ushortT u[8]; uint4 w; } t;
#pragma unroll
                    for (int j = 0; j < 8; j++) {
                        int k = (ch - 40) * 8 + j;
                        t.u[j] = (k < 147) ? f2b(fb[(size_t)(row0 + row) * 147 + k]) : (ushortT)0;
                    }
                    v = t.w;
                }
            } else if (MODE == 2) {
                if (ch >= 20) {                    // amsg, K in [160,480)
                    v = *(const uint4*)(amsg + (size_t)(row0 + row) * HP + (ch - 20) * 8);
                } else if (AUXP) {                 // faa, K in [0,160)
                    v = *(const uint4*)(aux + (size_t)(row0 + row) * 160 + ch * 8);
                } else {
                    union { ushortT u[8]; uint4 w; } t;
#pragma unroll
                    for (int j = 0; j < 8; j++) {
                        int k = ch * 8 + j;
                        t.u[j] = (k < 133) ? f2b(fa[(size_t)(row0 + row) * 133 + k]) : (ushortT)0;
                    }
                    v = t.w;
                }
            } else {                               // MODE 0: fbb
                if (AUXP) {
                    v = *(const uint4*)(aux + (size_t)(row0 + row) * 160 + ch * 8);
                } else {
                    union { ushortT u[8]; uint4 w; } t;
#pragma unroll
                    for (int j = 0; j < 8; j++) {
                        int k = ch * 8 + j;
                        t.u[j] = (k < 147) ? f2b(fb[(size_t)(row0 + row) * 147 + k]) : (ushortT)0;
                    }
                    v = t.w;
                }
            }
            *(uint4*)&panel[row * SP + ch * 8] = v;
        }
    }

    // B staging: wave w owns 1KB chunks [w*5, w*5+5) of the 20KB tile (5 glds/wave)
    auto BSTAGE = [&](int kt, int buf) {
        const ushortT* bp = (kt < SPLIT) ? (Bpk1 + (size_t)kt * 10240)
                                         : (Bpk2 + (size_t)(kt - SPLIT) * 10240);
#pragma unroll
        for (int q = 0; q < 5; q++) {
            int chunk = (wave * 5 + q) * 512;
            glds16(bp + chunk + lane * 8, &Bl[buf][chunk]);
        }
    };

    f32x4 acc[10];
#pragma unroll
    for (int n = 0; n < 10; n++) acc[n] = (f32x4){0.f, 0.f, 0.f, 0.f};

    // ================= prologue 2: B(0) staged, all waves synced
    BSTAGE(0, 0);
    asm volatile("s_waitcnt vmcnt(0)" ::: "memory");
    __builtin_amdgcn_s_barrier();
    __builtin_amdgcn_sched_barrier(0);

    // ================= counted-vmcnt K-loop (2 raw barriers/ktile, no drain)
    const int arow = (wm * 16 + (lane & 15)) * SP;
#pragma unroll
    for (int kt = 0; kt < KT; kt++) {
        if (kt + 1 < KT) BSTAGE(kt + 1, (kt + 1) & 1);   // overwrites buf read at kt-1 (barrier B cleared it)
        if (kt > 0) {
            if (kt + 1 < KT) asm volatile("s_waitcnt vmcnt(5)" ::: "memory");  // kt done; kt+1 in flight
            else             asm volatile("s_waitcnt vmcnt(0)" ::: "memory");
            __builtin_amdgcn_s_barrier();                // [A] all waves' kt loads landed
            __builtin_amdgcn_sched_barrier(0);
        }
        bf16x8 a0 = *(bf16x8*)&panel[arow + kt * 32 + kg8];
        const ushortT* Bb = Bl[kt & 1];
        __builtin_amdgcn_s_setprio(1);
#pragma unroll
        for (int n = 0; n < 10; n++) {
            bf16x8 b = *(bf16x8*)&Bb[(wn * 10 + n) * 512 + (lane >> 4) * 128 + (lane & 15) * 8];
            // swapped operands: acc holds C^T fragments
            acc[n] = __builtin_amdgcn_mfma_f32_16x16x32_bf16(b, a0, acc[n], 0, 0, 0);
        }
        __builtin_amdgcn_s_setprio(0);
        __builtin_amdgcn_s_barrier();                    // [B] readers of buf[kt&1] done
        __builtin_amdgcn_sched_barrier(0);
    }

    // ================= epilogue: lane holds C[row = lane&15][cols (lane>>4)*4 + n*16 + 160wn]
    {
        size_t gr = (size_t)(row0 + wm * 16 + (lane & 15));
#pragma unroll
        for (int n = 0; n < 10; n++) {
            int col = wn * 160 + n * 16 + (lane >> 4) * 4;
            float4 v = make_float4(acc[n][0], acc[n][1], acc[n][2], acc[n][3]);
            if (MODE == 2) {
                float4 bias = *(const float4*)&bop[col];
                v.x += bias.x; v.y += bias.y; v.z += bias.z; v.w += bias.w;
            }
            ushort4 u;
            u.x = f2b(fmaxf(v.x, 0.f)); u.y = f2b(fmaxf(v.y, 0.f));
            u.z = f2b(fmaxf(v.z, 0.f)); u.w = f2b(fmaxf(v.w, 0.f));
            *(ushort4*)&outp[gr * HP + col] = u;
        }
    }
}

// ---------------------------------------------------------------- atom sum (bf16 in/out, fp32 accum)
__global__ __launch_bounds__(256) void k_atom_sum(
    const ushortT* __restrict__ msg, const int* __restrict__ a2b,
    ushortT* __restrict__ amsg, int nA) {
    int t = blockIdx.x * 256 + threadIdx.x;
    int a = t / 40, q = t - a * 40;
    if (a >= nA) return;
    float s[8];
#pragma unroll
    for (int e = 0; e < 8; e++) s[e] = 0.f;
#pragma unroll
    for (int j = 0; j < 6; j++) {
        int b = a2b[a * 6 + j];
        uint4 u = *(const uint4*)(msg + (size_t)b * HP + q * 8);
        s[0] += b2f(u.x & 0xffff); s[1] += b2f(u.x >> 16);
        s[2] += b2f(u.y & 0xffff); s[3] += b2f(u.y >> 16);
        s[4] += b2f(u.z & 0xffff); s[5] += b2f(u.z >> 16);
        s[6] += b2f(u.w & 0xffff); s[7] += b2f(u.w >> 16);
    }
    uint4 o;
    o.x = (unsigned)f2b(s[0]) | ((unsigned)f2b(s[1]) << 16);
    o.y = (unsigned)f2b(s[2]) | ((unsigned)f2b(s[3]) << 16);
    o.z = (unsigned)f2b(s[4]) | ((unsigned)f2b(s[5]) << 16);
    o.w = (unsigned)f2b(s[6]) | ((unsigned)f2b(s[7]) << 16);
    *(uint4*)(amsg + (size_t)a * HP + q * 8) = o;
}

// ---------------------------------------------------------------- mean pool (bf16 ah -> fp32 out), vectorized
__global__ __launch_bounds__(256) void k_pool(
    const ushortT* __restrict__ ah, float* __restrict__ out, int n_mols, int apm) {
    int t = blockIdx.x * 256 + threadIdx.x;
    int m = t / 75, c4 = t - m * 75;    // 75 float4-chunks of 300 cols
    if (m >= n_mols) return;
    float4 s = make_float4(0, 0, 0, 0);
    for (int u = 0; u < apm; u++) {
        ushort4 q = *(const ushort4*)&ah[(size_t)(m * apm + u) * HP + c4 * 4];
        s.x += b2f(q.x); s.y += b2f(q.y); s.z += b2f(q.z); s.w += b2f(q.w);
    }
    float inv = 1.0f / (float)apm;
    s.x *= inv; s.y *= inv; s.z *= inv; s.w *= inv;
    *(float4*)&out[(size_t)m * 300 + c4 * 4] = s;
}

// ---------------------------------------------------------------- launch
extern "C" void kernel_launch(void* const* d_in, const int* in_sizes, int n_in,
                              void* d_out, int out_size, void* d_ws, size_t ws_size,
                              hipStream_t stream) {
    const float* fa     = (const float*)d_in[0];
    const float* fb     = (const float*)d_in[1];
    const int*   a2b    = (const int*)d_in[2];
    const int*   b2a    = (const int*)d_in[3];
    const int*   b2revb = (const int*)d_in[4];
    const float* Wi     = (const float*)d_in[5];
    const float* Wh     = (const float*)d_in[6];
    const float* Wo     = (const float*)d_in[7];
    const float* bo     = (const float*)d_in[8];

    const int nA     = in_sizes[0] / 133;   // 200000
    const int nB     = in_sizes[1] / 147;   // 400000
    const int n_mols = out_size / 300;      // 10000
    const int apm    = nA / n_mols;         // 20

    char* p = (char*)d_ws;
    ushortT* Wipk = (ushortT*)p;  p += (size_t)51200 * 2;
    ushortT* Whpk = (ushortT*)p;  p += (size_t)102400 * 2;
    ushortT* Wopk = (ushortT*)p;  p += (size_t)153600 * 2;
    float*   bop  = (float*)p;    p += (size_t)HP * 4;
    p = (char*)(((uintptr_t)p + 255) & ~(uintptr_t)255);

    const size_t msgBytes  = (size_t)nB * HP * 2;
    const size_t amsgBytes = (size_t)nA * HP * 2;
    const size_t fbbBytes  = (size_t)nB * 160 * 2;
    const size_t faaBytes  = (size_t)nA * 160 * 2;
    const size_t headBytes = (size_t)(p - (char*)d_ws);
    const size_t baseNeed  = headBytes + 2 * msgBytes + amsgBytes;
    const bool use_fbb = ws_size >= baseNeed + fbbBytes;
    const bool use_faa = ws_size >= baseNeed + fbbBytes + faaBytes;

    ushortT* msgA = (ushortT*)p;  p += msgBytes;
    ushortT* msgB = (ushortT*)p;  p += msgBytes;
    ushortT* amsg = (ushortT*)p;  p += amsgBytes;
    ushortT* fbb  = use_fbb ? (ushortT*)p : nullptr;  p += use_fbb ? fbbBytes : 0;
    ushortT* faa  = use_faa ? (ushortT*)p : nullptr;
    ushortT* ah   = msgB;           // msgB dead after depth-2 GEMM consumes it
    float*   out  = (float*)d_out;

    k_pack_weights<<<600, 256, 0, stream>>>(Wi, Wh, Wo, bo, Wipk, Whpk, Wopk, bop);
    if (use_fbb)
        k_pack_feat<147><<<(nB * 20 + 255) / 256, 256, 0, stream>>>(fb, fbb, nB);
    if (use_faa)
        k_pack_feat<133><<<(nA * 20 + 255) / 256, 256, 0, stream>>>(fa, faa, nA);

    const int asum_grid = (int)(((size_t)nA * 40 + 255) / 256);
    const int gB = nB / 32, gA = nA / 32;

    // GEMM1: msgA = relu(fbb @ Wi)
    if (use_fbb)
        k_mfma<0, true ><<<gB, 256, 0, stream>>>(fa, fb, fbb, nullptr, nullptr, nullptr, nullptr,
                                                 Wipk, Wipk, bop, msgA);
    else
        k_mfma<0, false><<<gB, 256, 0, stream>>>(fa, fb, nullptr, nullptr, nullptr, nullptr, nullptr,
                                                 Wipk, Wipk, bop, msgA);

    // depth 1: msgA -> msgB
    k_atom_sum<<<asum_grid, 256, 0, stream>>>(msgA, a2b, amsg, nA);
    if (use_fbb)
        k_mfma<1, true ><<<gB, 256, 0, stream>>>(fa, fb, fbb, amsg, msgA, b2a, b2revb,
                                                 Whpk, Wipk, bop, msgB);
    else
        k_mfma<1, false><<<gB, 256, 0, stream>>>(fa, fb, nullptr, amsg, msgA, b2a, b2revb,
                                                 Whpk, Wipk, bop, msgB);

    // depth 2: msgB -> msgA
    k_atom_sum<<<asum_grid, 256, 0, stream>>>(msgB, a2b, amsg, nA);
    if (use_fbb)
        k_mfma<1, true ><<<gB, 256, 0, stream>>>(fa, fb, fbb, amsg, msgB, b2a, b2revb,
                                                 Whpk, Wipk, bop, msgA);
    else
        k_mfma<1, false><<<gB, 256, 0, stream>>>(fa, fb, nullptr, amsg, msgB, b2a, b2revb,
                                                 Whpk, Wipk, bop, msgA);

    // readout: ah(bf16) = relu(concat @ Wo + b)
    k_atom_sum<<<asum_grid, 256, 0, stream>>>(msgA, a2b, amsg, nA);
    if (use_faa)
        k_mfma<2, true ><<<gA, 256, 0, stream>>>(fa, fb, faa, amsg, nullptr, nullptr, nullptr,
                                                 Wopk, Wopk, bop, ah);
    else
        k_mfma<2, false><<<gA, 256, 0, stream>>>(fa, fb, nullptr, amsg, nullptr, nullptr, nullptr,
                                                 Wopk, Wopk, bop, ah);
    k_pool<<<((n_mols * 75) + 255) / 256, 256, 0, stream>>>(ah, out, n_mols, apm);
}

// Round 14
// 1329.203 us; speedup vs baseline: 1.5553x; 1.5553x over previous
//
#include <hip/hip_runtime.h>
#include <hip/hip_bf16.h>
#include <cstdint>
#include <cstddef>

#define HP 320   // padded hidden/N dim (300 -> 320)

typedef unsigned short ushortT;
typedef __attribute__((ext_vector_type(8))) __bf16 bf16x8;
typedef __attribute__((ext_vector_type(4))) float f32x4;

__device__ __forceinline__ float b2f(unsigned u) {
    union { unsigned i; float f; } v; v.i = u << 16; return v.f;
}
__device__ __forceinline__ ushortT f2b(float f) {
    union { float f; unsigned i; } v; v.f = f;
    unsigned x = v.i;
    return (ushortT)((x + 0x7fffu + ((x >> 16) & 1u)) >> 16);
}
__device__ __forceinline__ unsigned subpk(unsigned a, unsigned r) {
    union { unsigned i; float f; } al, ah, rl, rh;
    al.i = a << 16; ah.i = a & 0xffff0000u;
    rl.i = r << 16; rh.i = r & 0xffff0000u;
    float lo = al.f - rl.f, hi = ah.f - rh.f;
    return (unsigned)f2b(lo) | ((unsigned)f2b(hi) << 16);
}
__device__ __forceinline__ uint4 subpk4(uint4 a, uint4 r) {
    uint4 o;
    o.x = subpk(a.x, r.x); o.y = subpk(a.y, r.y);
    o.z = subpk(a.z, r.z); o.w = subpk(a.w, r.w);
    return o;
}

// ---------------------------------------------------------------- pack weights into MFMA B-fragment order
// packed[kt][nt(20)][kg(4)][col(16)][j(8)]  ==  W[kt*32+kg*8+j][nt*16+col]
__device__ __forceinline__ void pack_one(int idx, const float* __restrict__ W,
                                         int Ksrc, ushortT* __restrict__ dst) {
    int j = idx & 7, col = (idx >> 3) & 15, kg = (idx >> 7) & 3;
    int t = idx >> 9; int nt = t % 20, kt = t / 20;
    int k = kt * 32 + kg * 8 + j, n = nt * 16 + col;
    float v = (k < Ksrc && n < 300) ? W[k * 300 + n] : 0.f;
    dst[idx] = f2b(v);
}
// W_o remap: logical k<133 -> fa rows (src k), k in [160,460) -> amsg rows (src k-27), else 0
__device__ __forceinline__ void pack_wo(int idx, const float* __restrict__ W,
                                        ushortT* __restrict__ dst) {
    int j = idx & 7, col = (idx >> 3) & 15, kg = (idx >> 7) & 3;
    int t = idx >> 9; int nt = t % 20, kt = t / 20;
    int k = kt * 32 + kg * 8 + j, n = nt * 16 + col;
    int src = (k < 133) ? k : ((k >= 160 && k < 460) ? (k - 27) : -1);
    float v = (src >= 0 && n < 300) ? W[src * 300 + n] : 0.f;
    dst[idx] = f2b(v);
}

__global__ __launch_bounds__(256) void k_pack_weights(
    const float* __restrict__ Wi, const float* __restrict__ Wh,
    const float* __restrict__ Wo, const float* __restrict__ bo,
    ushortT* __restrict__ Wipk, ushortT* __restrict__ Whpk,
    ushortT* __restrict__ Wopk, float* __restrict__ bop) {
    int idx = blockIdx.x * 256 + threadIdx.x;
    if (idx < 51200)  pack_one(idx, Wi, 147, Wipk);   // K1 = 160 (5 ktiles)
    if (idx < 102400) pack_one(idx, Wh, 300, Whpk);   // K2 = 320 (10 ktiles)
    if (idx < 153600) pack_wo(idx, Wo, Wopk);         // K3 = 480 (15 ktiles)
    if (idx < HP) bop[idx] = (idx < 300) ? bo[idx] : 0.f;
}

// ---------------------------------------------------------------- pre-pack fp32 features -> bf16 [rows][160]
template <int FD>   // 147 (f_bonds) or 133 (f_atoms)
__global__ __launch_bounds__(256) void k_pack_feat(
    const float* __restrict__ src, ushortT* __restrict__ dst, int nrows) {
    int t = blockIdx.x * 256 + threadIdx.x;
    if (t >= nrows * 20) return;
    int row = t / 20, q = t - row * 20;
    int k0 = q * 8;
    union { ushortT u[8]; uint4 v; } o;
#pragma unroll
    for (int j = 0; j < 8; j++) {
        int k = k0 + j;
        o.u[j] = (k < FD) ? f2b(src[(size_t)row * FD + k]) : (ushortT)0;
    }
    *(uint4*)(dst + (size_t)row * 160 + k0) = o.v;
}

// ---------------------------------------------------------------- unified MFMA GEMM: 4-MFMA-per-B-load geometry
// R7's proven shell (barrier-free K-loop, B reg-dbuf from L2, LDS A-panel, 3 blocks/CU)
// with waves split over N 4-way: wave = 64 rows x 80 cols, acc[4][5] (80 AGPR, same as
// R7), B-loads per kt HALVED (5 vs 10) and prefetch distance doubled (full kt = 20
// MFMAs). All A reads come from the panel; MODE1's fbb-recompute phase restages the
// (dead) diff panel mid-loop.
// MODE 0: panel = fbb (K=160), B=Wipk.                 out: msg = relu(A@Wi)
// MODE 1: panel = amsg[b2a]-msg[b2revb] (K=320) then fbb (K=160), B=[Whpk|Wipk].
//         out: msg = relu(diff@Wh + fb@Wi)
// MODE 2: panel = [faa K=160 | amsg K=320], B=Wopk.    out: ah = relu(A@Wo+b)
template <int MODE, bool AUXP>
__global__ __launch_bounds__(256, 3) void k_mfma(
    const float* __restrict__ fa, const float* __restrict__ fb,
    const ushortT* __restrict__ aux,
    const ushortT* __restrict__ amsg, const ushortT* __restrict__ msgin,
    const int* __restrict__ b2a, const int* __restrict__ b2revb,
    const ushortT* __restrict__ Bpk1, const ushortT* __restrict__ Bpk2,
    const float* __restrict__ bop,
    ushortT* __restrict__ outp) {
    constexpr int KT = (MODE == 0) ? 5 : 15;                       // total ktiles
    constexpr int SPLIT = (MODE == 1) ? 10 : KT;                   // B source switch
    constexpr int SP = (MODE == 0) ? 168 : ((MODE == 1) ? 328 : 488);  // panel stride
    __shared__ __align__(16) ushortT panel[64 * SP];   // 21 / 42 / 62.5 KB

    const int tid = threadIdx.x, wave = tid >> 6, lane = tid & 63;
    const int row0 = blockIdx.x * 64;
    const int kg8 = (lane >> 4) * 8;
    const int l15 = lane & 15;

    // ================= prologue: stage A panel
    if (MODE == 1) {
#pragma unroll
        for (int it = 0; it < 10; it++) {
            int flat = tid + 256 * it;             // 64 rows * 40 chunks
            int row = flat / 40, ch = flat - row * 40;
            size_t oa = (size_t)b2a[row0 + row] * HP;
            size_t orv = (size_t)b2revb[row0 + row] * HP;
            uint4 ua = *(const uint4*)(amsg + oa + ch * 8);
            uint4 ur = *(const uint4*)(msgin + orv + ch * 8);
            *(uint4*)&panel[row * SP + ch * 8] = subpk4(ua, ur);
        }
    } else if (MODE == 0) {
#pragma unroll
        for (int it = 0; it < 5; it++) {
            int flat = tid + 256 * it;             // 64 rows * 20 chunks
            int row = flat / 20, ch = flat - row * 20;
            uint4 v;
            if (AUXP) {
                v = *(const uint4*)(aux + (size_t)(row0 + row) * 160 + ch * 8);
            } else {
                union { ushortT u[8]; uint4 w; } t;
#pragma unroll
                for (int j = 0; j < 8; j++) {
                    int k = ch * 8 + j;
                    t.u[j] = (k < 147) ? f2b(fb[(size_t)(row0 + row) * 147 + k]) : (ushortT)0;
                }
                v = t.w;
            }
            *(uint4*)&panel[row * SP + ch * 8] = v;
        }
    } else {   // MODE 2: [faa | amsg], K = 480
#pragma unroll
        for (int it = 0; it < 15; it++) {
            int flat = tid + 256 * it;             // 64 rows * 60 chunks
            int row = flat / 60, ch = flat - row * 60;
            uint4 v;
            if (ch >= 20) {
                v = *(const uint4*)(amsg + (size_t)(row0 + row) * HP + (ch - 20) * 8);
            } else if (AUXP) {
                v = *(const uint4*)(aux + (size_t)(row0 + row) * 160 + ch * 8);
            } else {
                union { ushortT u[8]; uint4 w; } t;
#pragma unroll
                for (int j = 0; j < 8; j++) {
                    int k = ch * 8 + j;
                    t.u[j] = (k < 133) ? f2b(fa[(size_t)(row0 + row) * 133 + k]) : (ushortT)0;
                }
                v = t.w;
            }
            *(uint4*)&panel[row * SP + ch * 8] = v;
        }
    }

    f32x4 acc[4][5];
#pragma unroll
    for (int i = 0; i < 4; i++)
#pragma unroll
        for (int n = 0; n < 5; n++) acc[i][n] = (f32x4){0.f, 0.f, 0.f, 0.f};

    uint4 breg[2][5];    // full-kt B dbuf: wave's 5 n-tiles (40 VGPR)
    const int boff = wave * 5 * 512 + (lane >> 4) * 128 + l15 * 8;

#define LOADB(kt, buf)                                                               \
    {                                                                                \
        const ushortT* bp = ((kt) < SPLIT) ? (Bpk1 + (size_t)(kt) * 10240)           \
                                           : (Bpk2 + (size_t)((kt) - SPLIT) * 10240);\
        _Pragma("unroll")                                                            \
        for (int n = 0; n < 5; n++)                                                  \
            breg[buf][n] = *(const uint4*)(bp + boff + n * 512);                     \
    }

    // one ktile: 4 a-frags from panel, 20 MFMAs on breg[bufi]
#define MSTEP(bufi, pk0)                                                             \
    {                                                                                \
        bf16x8 a0 = *(bf16x8*)&panel[(l15) * SP + (pk0) + kg8];                      \
        bf16x8 a1 = *(bf16x8*)&panel[(16 + l15) * SP + (pk0) + kg8];                 \
        bf16x8 a2 = *(bf16x8*)&panel[(32 + l15) * SP + (pk0) + kg8];                 \
        bf16x8 a3 = *(bf16x8*)&panel[(48 + l15) * SP + (pk0) + kg8];                 \
        __builtin_amdgcn_s_setprio(1);                                               \
        _Pragma("unroll")                                                            \
        for (int n = 0; n < 5; n++) {                                                \
            bf16x8 b;                                                                \
            *(uint4*)&b = breg[bufi][n];                                             \
            acc[0][n] = __builtin_amdgcn_mfma_f32_16x16x32_bf16(b, a0, acc[0][n], 0, 0, 0); \
            acc[1][n] = __builtin_amdgcn_mfma_f32_16x16x32_bf16(b, a1, acc[1][n], 0, 0, 0); \
            acc[2][n] = __builtin_amdgcn_mfma_f32_16x16x32_bf16(b, a2, acc[2][n], 0, 0, 0); \
            acc[3][n] = __builtin_amdgcn_mfma_f32_16x16x32_bf16(b, a3, acc[3][n], 0, 0, 0); \
        }                                                                            \
        __builtin_amdgcn_s_setprio(0);                                               \
    }

    LOADB(0, 0);
    __syncthreads();   // panel + (B0 in regs via compiler waitcnt)

    if (MODE == 1) {
        // phase 1: gathered diff @ Wh (kt 0..9), A from panel at kt*32
#pragma unroll
        for (int kt = 0; kt < 10; kt++) {
            LOADB(kt + 1, (kt + 1) & 1);           // kt+1 <= 10, always valid
            MSTEP(kt & 1, kt * 32);
        }
        __syncthreads();                           // all panel readers done
        // restage fbb (K=160) into dead panel cols [0,160)
#pragma unroll
        for (int it = 0; it < 5; it++) {
            int flat = tid + 256 * it;
            int row = flat / 20, ch = flat - row * 20;
            uint4 v;
            if (AUXP) {
                v = *(const uint4*)(aux + (size_t)(row0 + row) * 160 + ch * 8);
            } else {
                union { ushortT u[8]; uint4 w; } t;
#pragma unroll
                for (int j = 0; j < 8; j++) {
                    int k = ch * 8 + j;
                    t.u[j] = (k < 147) ? f2b(fb[(size_t)(row0 + row) * 147 + k]) : (ushortT)0;
                }
                v = t.w;
            }
            *(uint4*)&panel[row * SP + ch * 8] = v;
        }
        __syncthreads();
        // phase 2: fbb @ Wi (kt 10..14), A from panel at (kt-10)*32
#pragma unroll
        for (int kt = 10; kt < 15; kt++) {
            if (kt + 1 < 15) LOADB(kt + 1, (kt + 1) & 1);
            MSTEP(kt & 1, (kt - 10) * 32);
        }
    } else {
#pragma unroll
        for (int kt = 0; kt < KT; kt++) {
            if (kt + 1 < KT) LOADB(kt + 1, (kt + 1) & 1);
            MSTEP(kt & 1, kt * 32);
        }
    }
#undef LOADB
#undef MSTEP

    // ================= epilogue: lane holds C[row = l15 (+16i)][cols wave*80 + n*16 + (lane>>4)*4]
#pragma unroll
    for (int i = 0; i < 4; i++) {
        size_t gr = (size_t)(row0 + i * 16 + l15);
#pragma unroll
        for (int n = 0; n < 5; n++) {
            int col = wave * 80 + n * 16 + (lane >> 4) * 4;
            float4 v = make_float4(acc[i][n][0], acc[i][n][1], acc[i][n][2], acc[i][n][3]);
            if (MODE == 2) {
                float4 bias = *(const float4*)&bop[col];
                v.x += bias.x; v.y += bias.y; v.z += bias.z; v.w += bias.w;
            }
            ushort4 u;
            u.x = f2b(fmaxf(v.x, 0.f)); u.y = f2b(fmaxf(v.y, 0.f));
            u.z = f2b(fmaxf(v.z, 0.f)); u.w = f2b(fmaxf(v.w, 0.f));
            *(ushort4*)&outp[gr * HP + col] = u;
        }
    }
}

// ---------------------------------------------------------------- atom sum (bf16 in/out, fp32 accum)
__global__ __launch_bounds__(256) void k_atom_sum(
    const ushortT* __restrict__ msg, const int* __restrict__ a2b,
    ushortT* __restrict__ amsg, int nA) {
    int t = blockIdx.x * 256 + threadIdx.x;
    int a = t / 40, q = t - a * 40;
    if (a >= nA) return;
    float s[8];
#pragma unroll
    for (int e = 0; e < 8; e++) s[e] = 0.f;
#pragma unroll
    for (int j = 0; j < 6; j++) {
        int b = a2b[a * 6 + j];
        uint4 u = *(const uint4*)(msg + (size_t)b * HP + q * 8);
        s[0] += b2f(u.x & 0xffff); s[1] += b2f(u.x >> 16);
        s[2] += b2f(u.y & 0xffff); s[3] += b2f(u.y >> 16);
        s[4] += b2f(u.z & 0xffff); s[5] += b2f(u.z >> 16);
        s[6] += b2f(u.w & 0xffff); s[7] += b2f(u.w >> 16);
    }
    uint4 o;
    o.x = (unsigned)f2b(s[0]) | ((unsigned)f2b(s[1]) << 16);
    o.y = (unsigned)f2b(s[2]) | ((unsigned)f2b(s[3]) << 16);
    o.z = (unsigned)f2b(s[4]) | ((unsigned)f2b(s[5]) << 16);
    o.w = (unsigned)f2b(s[6]) | ((unsigned)f2b(s[7]) << 16);
    *(uint4*)(amsg + (size_t)a * HP + q * 8) = o;
}

// ---------------------------------------------------------------- mean pool (bf16 ah -> fp32 out), vectorized
__global__ __launch_bounds__(256) void k_pool(
    const ushortT* __restrict__ ah, float* __restrict__ out, int n_mols, int apm) {
    int t = blockIdx.x * 256 + threadIdx.x;
    int m = t / 75, c4 = t - m * 75;    // 75 float4-chunks of 300 cols
    if (m >= n_mols) return;
    float4 s = make_float4(0, 0, 0, 0);
    for (int u = 0; u < apm; u++) {
        ushort4 q = *(const ushort4*)&ah[(size_t)(m * apm + u) * HP + c4 * 4];
        s.x += b2f(q.x); s.y += b2f(q.y); s.z += b2f(q.z); s.w += b2f(q.w);
    }
    float inv = 1.0f / (float)apm;
    s.x *= inv; s.y *= inv; s.z *= inv; s.w *= inv;
    *(float4*)&out[(size_t)m * 300 + c4 * 4] = s;
}

// ---------------------------------------------------------------- launch
extern "C" void kernel_launch(void* const* d_in, const int* in_sizes, int n_in,
                              void* d_out, int out_size, void* d_ws, size_t ws_size,
                              hipStream_t stream) {
    const float* fa     = (const float*)d_in[0];
    const float* fb     = (const float*)d_in[1];
    const int*   a2b    = (const int*)d_in[2];
    const int*   b2a    = (const int*)d_in[3];
    const int*   b2revb = (const int*)d_in[4];
    const float* Wi     = (const float*)d_in[5];
    const float* Wh     = (const float*)d_in[6];
    const float* Wo     = (const float*)d_in[7];
    const float* bo     = (const float*)d_in[8];

    const int nA     = in_sizes[0] / 133;   // 200000
    const int nB     = in_sizes[1] / 147;   // 400000
    const int n_mols = out_size / 300;      // 10000
    const int apm    = nA / n_mols;         // 20

    char* p = (char*)d_ws;
    ushortT* Wipk = (ushortT*)p;  p += (size_t)51200 * 2;
    ushortT* Whpk = (ushortT*)p;  p += (size_t)102400 * 2;
    ushortT* Wopk = (ushortT*)p;  p += (size_t)153600 * 2;
    float*   bop  = (float*)p;    p += (size_t)HP * 4;
    p = (char*)(((uintptr_t)p + 255) & ~(uintptr_t)255);

    const size_t msgBytes  = (size_t)nB * HP * 2;
    const size_t amsgBytes = (size_t)nA * HP * 2;
    const size_t fbbBytes  = (size_t)nB * 160 * 2;
    const size_t faaBytes  = (size_t)nA * 160 * 2;
    const size_t headBytes = (size_t)(p - (char*)d_ws);
    const size_t baseNeed  = headBytes + 2 * msgBytes + amsgBytes;
    const bool use_fbb = ws_size >= baseNeed + fbbBytes;
    const bool use_faa = ws_size >= baseNeed + fbbBytes + faaBytes;

    ushortT* msgA = (ushortT*)p;  p += msgBytes;
    ushortT* msgB = (ushortT*)p;  p += msgBytes;
    ushortT* amsg = (ushortT*)p;  p += amsgBytes;
    ushortT* fbb  = use_fbb ? (ushortT*)p : nullptr;  p += use_fbb ? fbbBytes : 0;
    ushortT* faa  = use_faa ? (ushortT*)p : nullptr;
    ushortT* ah   = msgB;           // msgB dead after depth-2 GEMM consumes it
    float*   out  = (float*)d_out;

    k_pack_weights<<<600, 256, 0, stream>>>(Wi, Wh, Wo, bo, Wipk, Whpk, Wopk, bop);
    if (use_fbb)
        k_pack_feat<147><<<(nB * 20 + 255) / 256, 256, 0, stream>>>(fb, fbb, nB);
    if (use_faa)
        k_pack_feat<133><<<(nA * 20 + 255) / 256, 256, 0, stream>>>(fa, faa, nA);

    const int asum_grid = (int)(((size_t)nA * 40 + 255) / 256);
    const int gB = nB / 64, gA = nA / 64;

    // GEMM1: msgA = relu(fbb @ Wi)
    if (use_fbb)
        k_mfma<0, true ><<<gB, 256, 0, stream>>>(fa, fb, fbb, nullptr, nullptr, nullptr, nullptr,
                                                 Wipk, Wipk, bop, msgA);
    else
        k_mfma<0, false><<<gB, 256, 0, stream>>>(fa, fb, nullptr, nullptr, nullptr, nullptr, nullptr,
                                                 Wipk, Wipk, bop, msgA);

    // depth 1: msgA -> msgB
    k_atom_sum<<<asum_grid, 256, 0, stream>>>(msgA, a2b, amsg, nA);
    if (use_fbb)
        k_mfma<1, true ><<<gB, 256, 0, stream>>>(fa, fb, fbb, amsg, msgA, b2a, b2revb,
                                                 Whpk, Wipk, bop, msgB);
    else
        k_mfma<1, false><<<gB, 256, 0, stream>>>(fa, fb, nullptr, amsg, msgA, b2a, b2revb,
                                                 Whpk, Wipk, bop, msgB);

    // depth 2: msgB -> msgA
    k_atom_sum<<<asum_grid, 256, 0, stream>>>(msgB, a2b, amsg, nA);
    if (use_fbb)
        k_mfma<1, true ><<<gB, 256, 0, stream>>>(fa, fb, fbb, amsg, msgB, b2a, b2revb,
                                                 Whpk, Wipk, bop, msgA);
    else
        k_mfma<1, false><<<gB, 256, 0, stream>>>(fa, fb, nullptr, amsg, msgB, b2a, b2revb,
                                                 Whpk, Wipk, bop, msgA);

    // readout: ah(bf16) = relu(concat @ Wo + b)
    k_atom_sum<<<asum_grid, 256, 0, stream>>>(msgA, a2b, amsg, nA);
    if (use_faa)
        k_mfma<2, true ><<<gA, 256, 0, stream>>>(fa, fb, faa, amsg, nullptr, nullptr, nullptr,
                                                 Wopk, Wopk, bop, ah);
    else
        k_mfma<2, false><<<gA, 256, 0, stream>>>(fa, fb, nullptr, amsg, nullptr, nullptr, nullptr,
                                                 Wopk, Wopk, bop, ah);
    k_pool<<<((n_mols * 75) + 255) / 256, 256, 0, stream>>>(ah, out, n_mols, apm);
}